// Round 10
// baseline (203.731 us; speedup 1.0000x reference)
//
#include <hip/hip_runtime.h>
#include <cmath>

#define B_SZ 512
#define D_SZ 128
#define K_SZ 4096
#define NDATA 500000
#define TEMP 0.07f
#define MOM 0.5f
#define EPSN 1e-12f
#define SPLIT 8
#define WSB_OFF (1 << 20)   // fp8 shadow bank offset in d_ws (bytes)
#define NH 300000           // row split: phase A emits rows [0,NH)
#define M_SENT -1.0e30f     // finite sentinel for online-LSE max
#define D_INV  -3.0e30f     // invalid-logit sentinel (exp underflows to 0)

typedef float f32x4 __attribute__((ext_vector_type(4)));
typedef float f32x2 __attribute__((ext_vector_type(2)));

// ---------------- kernel A: normalize s,t + pos logits ----------------
__global__ void knorm(const float* __restrict__ s_in, const float* __restrict__ t_in,
                      float* __restrict__ s_n, float* __restrict__ t_n,
                      float* __restrict__ pos) {
    int b = blockIdx.x;
    int l = threadIdx.x;  // 64 lanes, 2 floats each
    float2 sv = ((const float2*)(s_in + b * D_SZ))[l];
    float2 tv = ((const float2*)(t_in + b * D_SZ))[l];
    float ss = sv.x * sv.x + sv.y * sv.y;
    float tt = tv.x * tv.x + tv.y * tv.y;
    for (int m = 1; m < 64; m <<= 1) {
        ss += __shfl_xor(ss, m, 64);
        tt += __shfl_xor(tt, m, 64);
    }
    float sinv = 1.0f / fmaxf(sqrtf(ss), EPSN);
    float tinv = 1.0f / fmaxf(sqrtf(tt), EPSN);
    float2 sn = {sv.x * sinv, sv.y * sinv};
    float2 tn = {tv.x * tinv, tv.y * tinv};
    ((float2*)(s_n + b * D_SZ))[l] = sn;
    ((float2*)(t_n + b * D_SZ))[l] = tn;
    float d = sn.x * tn.x + sn.y * tn.y;
    for (int m = 1; m < 64; m <<= 1) d += __shfl_xor(d, m, 64);
    if (l == 0) pos[b] = d * (1.0f / TEMP);
}

// ---------------- copy+emit body over vector range [j0, j1) ----------------
__device__ __forceinline__ void copy_emit_range(const float* __restrict__ src,
                                                float* __restrict__ out,
                                                unsigned int* __restrict__ wsb,
                                                long long j0, long long j1,
                                                long long t, long long nthr, int lane) {
    const long long total = (long long)NDATA * D_SZ;
    const f32x4* src4 = (const f32x4*)src;
    f32x4* out4 = (f32x4*)out;
    for (long long j = j0 + t; j < j1; j += nthr) {
        f32x4 v = __builtin_nontemporal_load(src4 + j);
        int w8 = __builtin_amdgcn_cvt_pk_fp8_f32(v.x, v.y, 0, false);
        w8 = __builtin_amdgcn_cvt_pk_fp8_f32(v.z, v.w, w8, true);
        wsb[j] = (unsigned int)w8;  // regular store -> L3-resident for gather
        float pw = __shfl_up(v.w, 1, 64);
        if (lane == 0 && j > 0) pw = src[4 * j - 1];
        if (j > 0) {
            f32x4 w;
            w.x = pw; w.y = v.x; w.z = v.y; w.w = v.z;
            __builtin_nontemporal_store(w, out4 + j);
        } else {
            out[1] = v.x; out[2] = v.y; out[3] = v.z;
            out[total] = src[total - 1];
        }
    }
}

// ---------------- gather body over one (b,split), entries filtered by LO ----------------
template <bool LO>
__device__ __forceinline__ void gather_body(const unsigned int* __restrict__ wsb,
                                            const int* __restrict__ negidx,
                                            const float* __restrict__ s_n,
                                            float2* __restrict__ partials,
                                            int split, int b, int tid) {
    const int oct = tid >> 3;  // 32 octets of 8 lanes
    const int o = tid & 7;
    const f32x4* sn4 = (const f32x4*)(s_n + b * D_SZ + o * 16);
    f32x4 s0 = sn4[0], s1 = sn4[1], s2 = sn4[2], s3 = sn4[3];
    float m = M_SENT, ssum = 0.0f;
    const int KB = K_SZ / SPLIT;             // 512
    const int base = b * K_SZ + split * KB;
    for (int it = 0; it < KB / 128; ++it) {  // 4 iters; octet does 4 rows/iter
        int k = it * 128 + oct * 4;
        int4 idx = *(const int4*)(negidx + base + k);
        bool c0 = LO ? (idx.x < NH) : (idx.x >= NH);
        bool c1 = LO ? (idx.y < NH) : (idx.y >= NH);
        bool c2 = LO ? (idx.z < NH) : (idx.z >= NH);
        bool c3 = LO ? (idx.w < NH) : (idx.w >= NH);
        long long i0 = c0 ? (long long)idx.x : 0;
        long long i1 = c1 ? (long long)idx.y : 0;
        long long i2 = c2 ? (long long)idx.z : 0;
        long long i3 = c3 ? (long long)idx.w : 0;
        uint4 h0 = ((const uint4*)(wsb + i0 * 32))[o];
        uint4 h1 = ((const uint4*)(wsb + i1 * 32))[o];
        uint4 h2 = ((const uint4*)(wsb + i2 * 32))[o];
        uint4 h3 = ((const uint4*)(wsb + i3 * 32))[o];
        float d0 = 0.0f, d1 = 0.0f, d2 = 0.0f, d3 = 0.0f;
        f32x2 a, c;
        a = __builtin_amdgcn_cvt_pk_f32_fp8((int)h0.x, false);
        c = __builtin_amdgcn_cvt_pk_f32_fp8((int)h0.x, true);
        d0 += a.x * s0.x + a.y * s0.y + c.x * s0.z + c.y * s0.w;
        a = __builtin_amdgcn_cvt_pk_f32_fp8((int)h0.y, false);
        c = __builtin_amdgcn_cvt_pk_f32_fp8((int)h0.y, true);
        d0 += a.x * s1.x + a.y * s1.y + c.x * s1.z + c.y * s1.w;
        a = __builtin_amdgcn_cvt_pk_f32_fp8((int)h0.z, false);
        c = __builtin_amdgcn_cvt_pk_f32_fp8((int)h0.z, true);
        d0 += a.x * s2.x + a.y * s2.y + c.x * s2.z + c.y * s2.w;
        a = __builtin_amdgcn_cvt_pk_f32_fp8((int)h0.w, false);
        c = __builtin_amdgcn_cvt_pk_f32_fp8((int)h0.w, true);
        d0 += a.x * s3.x + a.y * s3.y + c.x * s3.z + c.y * s3.w;

        a = __builtin_amdgcn_cvt_pk_f32_fp8((int)h1.x, false);
        c = __builtin_amdgcn_cvt_pk_f32_fp8((int)h1.x, true);
        d1 += a.x * s0.x + a.y * s0.y + c.x * s0.z + c.y * s0.w;
        a = __builtin_amdgcn_cvt_pk_f32_fp8((int)h1.y, false);
        c = __builtin_amdgcn_cvt_pk_f32_fp8((int)h1.y, true);
        d1 += a.x * s1.x + a.y * s1.y + c.x * s1.z + c.y * s1.w;
        a = __builtin_amdgcn_cvt_pk_f32_fp8((int)h1.z, false);
        c = __builtin_amdgcn_cvt_pk_f32_fp8((int)h1.z, true);
        d1 += a.x * s2.x + a.y * s2.y + c.x * s2.z + c.y * s2.w;
        a = __builtin_amdgcn_cvt_pk_f32_fp8((int)h1.w, false);
        c = __builtin_amdgcn_cvt_pk_f32_fp8((int)h1.w, true);
        d1 += a.x * s3.x + a.y * s3.y + c.x * s3.z + c.y * s3.w;

        a = __builtin_amdgcn_cvt_pk_f32_fp8((int)h2.x, false);
        c = __builtin_amdgcn_cvt_pk_f32_fp8((int)h2.x, true);
        d2 += a.x * s0.x + a.y * s0.y + c.x * s0.z + c.y * s0.w;
        a = __builtin_amdgcn_cvt_pk_f32_fp8((int)h2.y, false);
        c = __builtin_amdgcn_cvt_pk_f32_fp8((int)h2.y, true);
        d2 += a.x * s1.x + a.y * s1.y + c.x * s1.z + c.y * s1.w;
        a = __builtin_amdgcn_cvt_pk_f32_fp8((int)h2.z, false);
        c = __builtin_amdgcn_cvt_pk_f32_fp8((int)h2.z, true);
        d2 += a.x * s2.x + a.y * s2.y + c.x * s2.z + c.y * s2.w;
        a = __builtin_amdgcn_cvt_pk_f32_fp8((int)h2.w, false);
        c = __builtin_amdgcn_cvt_pk_f32_fp8((int)h2.w, true);
        d2 += a.x * s3.x + a.y * s3.y + c.x * s3.z + c.y * s3.w;

        a = __builtin_amdgcn_cvt_pk_f32_fp8((int)h3.x, false);
        c = __builtin_amdgcn_cvt_pk_f32_fp8((int)h3.x, true);
        d3 += a.x * s0.x + a.y * s0.y + c.x * s0.z + c.y * s0.w;
        a = __builtin_amdgcn_cvt_pk_f32_fp8((int)h3.y, false);
        c = __builtin_amdgcn_cvt_pk_f32_fp8((int)h3.y, true);
        d3 += a.x * s1.x + a.y * s1.y + c.x * s1.z + c.y * s1.w;
        a = __builtin_amdgcn_cvt_pk_f32_fp8((int)h3.z, false);
        c = __builtin_amdgcn_cvt_pk_f32_fp8((int)h3.z, true);
        d3 += a.x * s2.x + a.y * s2.y + c.x * s2.z + c.y * s2.w;
        a = __builtin_amdgcn_cvt_pk_f32_fp8((int)h3.w, false);
        c = __builtin_amdgcn_cvt_pk_f32_fp8((int)h3.w, true);
        d3 += a.x * s3.x + a.y * s3.y + c.x * s3.z + c.y * s3.w;

        for (int s = 1; s < 8; s <<= 1) {
            d0 += __shfl_xor(d0, s, 64);
            d1 += __shfl_xor(d1, s, 64);
            d2 += __shfl_xor(d2, s, 64);
            d3 += __shfl_xor(d3, s, 64);
        }
        d0 = c0 ? d0 * (1.0f / TEMP) : D_INV;
        d1 = c1 ? d1 * (1.0f / TEMP) : D_INV;
        d2 = c2 ? d2 * (1.0f / TEMP) : D_INV;
        d3 = c3 ? d3 * (1.0f / TEMP) : D_INV;
        float mx = fmaxf(fmaxf(d0, d1), fmaxf(d2, d3));
        float mn = fmaxf(m, mx);
        ssum = ssum * __expf(m - mn) + __expf(d0 - mn) + __expf(d1 - mn) +
               __expf(d2 - mn) + __expf(d3 - mn);
        m = mn;
    }
    __shared__ float2 gp[32];
    if (o == 0) gp[oct] = make_float2(m, ssum);
    __syncthreads();
    if (tid == 0) {
        float M = gp[0].x, S = gp[0].y;
        for (int g = 1; g < 32; ++g) {
            float mg = gp[g].x, sg = gp[g].y;
            float mn = fmaxf(M, mg);
            S = S * __expf(M - mn) + sg * __expf(mg - mn);
            M = mn;
        }
        partials[b * SPLIT + split] = make_float2(M, S);
    }
}

// ---------------- phase A: copy+emit rows [0, NH) ----------------
__global__ __launch_bounds__(256) void kphaseA(const float* __restrict__ src,
                                               float* __restrict__ out,
                                               unsigned int* __restrict__ wsb) {
    const long long VH = (long long)NH * 32;
    long long t = blockIdx.x * 256LL + threadIdx.x;
    copy_emit_range(src, out, wsb, 0, VH, t, gridDim.x * 256LL, threadIdx.x & 63);
}

// ---------------- phase B: fused copy rows [NH,N) || gather idx<NH ----------------
// 6144 blocks: bid%3==0 -> copy (2048), else gather (4096 = SPLIT*B_SZ)
__global__ __launch_bounds__(256) void kphaseB(const float* __restrict__ src,
                                               float* __restrict__ out,
                                               unsigned int* __restrict__ wsb,
                                               const int* __restrict__ negidx,
                                               const float* __restrict__ s_n,
                                               float2* __restrict__ partials_lo) {
    const int r = blockIdx.x % 3;
    const int q = blockIdx.x / 3;
    if (r == 0) {
        const long long VH = (long long)NH * 32;
        const long long NV = (long long)NDATA * 32;
        long long t = q * 256LL + threadIdx.x;
        copy_emit_range(src, out, wsb, VH, NV, t, 2048LL * 256LL, threadIdx.x & 63);
    } else {
        const int g = 2 * q + (r - 1);  // [0, 4096)
        gather_body<true>(wsb, negidx, s_n, partials_lo, g & (SPLIT - 1), g >> 3, threadIdx.x);
    }
}

// ---------------- phase C: gather idx>=NH ----------------
__global__ __launch_bounds__(256) void kphaseC(const unsigned int* __restrict__ wsb,
                                               const int* __restrict__ negidx,
                                               const float* __restrict__ s_n,
                                               float2* __restrict__ partials_hi) {
    gather_body<false>(wsb, negidx, s_n, partials_hi, blockIdx.x, blockIdx.y, threadIdx.x);
}

// ---------------- momentum scatter-update (last-wins) ----------------
__global__ void kupdate(const int* __restrict__ indices, const float* __restrict__ bank,
                        const float* __restrict__ t_n, float* __restrict__ outBank /* d_out+1 */) {
    int j = blockIdx.x;
    int l = threadIdx.x;  // 64
    int idx = indices[j];
    for (int j2 = j + 1; j2 < B_SZ; ++j2)
        if (indices[j2] == idx) return;  // last occurrence wins
    float2 bv = ((const float2*)(bank + (long long)idx * D_SZ))[l];
    float2 tv = ((const float2*)(t_n + j * D_SZ))[l];
    float2 u = {MOM * bv.x + (1.0f - MOM) * tv.x, MOM * bv.y + (1.0f - MOM) * tv.y};
    float ss = u.x * u.x + u.y * u.y;
    for (int m = 1; m < 64; m <<= 1) ss += __shfl_xor(ss, m, 64);
    float inv = 1.0f / fmaxf(sqrtf(ss), EPSN);
    float* dst = outBank + (long long)idx * D_SZ + l * 2;
    dst[0] = u.x * inv;
    dst[1] = u.y * inv;
}

// ---------------- combine partials -> loss ----------------
__global__ void kfinal(const float2* __restrict__ plo, const float2* __restrict__ phi,
                       const float* __restrict__ pos, float* __restrict__ out) {
    __shared__ float red[B_SZ];
    int t = threadIdx.x;  // 512
    float M = M_SENT, S = 0.0f;
    for (int p = 0; p < SPLIT; ++p) {
        float2 ms = plo[t * SPLIT + p];
        float mn = fmaxf(M, ms.x);
        S = S * __expf(M - mn) + ms.y * __expf(ms.x - mn);
        M = mn;
        ms = phi[t * SPLIT + p];
        mn = fmaxf(M, ms.x);
        S = S * __expf(M - mn) + ms.y * __expf(ms.x - mn);
        M = mn;
    }
    float pl = pos[t];
    float mn = fmaxf(M, pl);
    S = S * __expf(M - mn) + __expf(pl - mn);
    M = mn;
    red[t] = M + logf(S) - pl;
    __syncthreads();
    for (int o = 256; o > 0; o >>= 1) {
        if (t < o) red[t] += red[t + o];
        __syncthreads();
    }
    if (t == 0) out[0] = red[0] * (1.0f / (float)B_SZ);
}

extern "C" void kernel_launch(void* const* d_in, const int* in_sizes, int n_in,
                              void* d_out, int out_size, void* d_ws, size_t ws_size,
                              hipStream_t stream) {
    const float* student = (const float*)d_in[0];
    const float* teacher = (const float*)d_in[1];
    const float* bank    = (const float*)d_in[2];
    const int*   indices = (const int*)d_in[3];
    const int*   negidx  = (const int*)d_in[4];
    float* out = (float*)d_out;

    // workspace: small arrays in first 1 MB, fp8 shadow bank after (61 MB)
    float* s_n       = (float*)d_ws;             // 65536 f
    float* t_n       = s_n + B_SZ * D_SZ;        // 65536 f
    float* pos       = t_n + B_SZ * D_SZ;        // 512 f
    float2* plo      = (float2*)(pos + B_SZ);    // 4096 float2
    float2* phi      = plo + B_SZ * SPLIT;       // 4096 float2
    unsigned int* wsb = (unsigned int*)((char*)d_ws + WSB_OFF);

    knorm<<<B_SZ, 64, 0, stream>>>(student, teacher, s_n, t_n, pos);
    kphaseA<<<4096, 256, 0, stream>>>(bank, out, wsb);
    kphaseB<<<6144, 256, 0, stream>>>(bank, out, wsb, negidx, s_n, plo);
    dim3 gc(SPLIT, B_SZ);
    kphaseC<<<gc, 256, 0, stream>>>(wsb, negidx, s_n, phi);
    kupdate<<<B_SZ, 64, 0, stream>>>(indices, bank, t_n, out + 1);
    kfinal<<<1, B_SZ, 0, stream>>>(plo, phi, pos, out);
}

// Round 11
// 178.824 us; speedup vs baseline: 1.1393x; 1.1393x over previous
//
#include <hip/hip_runtime.h>
#include <cmath>

#define B_SZ 512
#define D_SZ 128
#define K_SZ 4096
#define NDATA 500000
#define TEMP 0.07f
#define MOM 0.5f
#define EPSN 1e-12f
#define SPLIT 8
#define WSB_OFF (1 << 20)  // fp8 shadow bank offset in d_ws (bytes)
#define NV_TOT 16000000LL  // total float4 vectors in bank
#define TILE_V 1024LL      // vectors per wave tile (64 lanes x 16 iters)
#define NTILE 15625LL      // NV_TOT / TILE_V, exact

typedef float f32x4 __attribute__((ext_vector_type(4)));
typedef float f32x2 __attribute__((ext_vector_type(2)));

// ---------------- kernel A: normalize s,t + pos logits ----------------
__global__ void knorm(const float* __restrict__ s_in, const float* __restrict__ t_in,
                      float* __restrict__ s_n, float* __restrict__ t_n,
                      float* __restrict__ pos) {
    int b = blockIdx.x;
    int l = threadIdx.x;  // 64 lanes, 2 floats each
    float2 sv = ((const float2*)(s_in + b * D_SZ))[l];
    float2 tv = ((const float2*)(t_in + b * D_SZ))[l];
    float ss = sv.x * sv.x + sv.y * sv.y;
    float tt = tv.x * tv.x + tv.y * tv.y;
    for (int m = 1; m < 64; m <<= 1) {
        ss += __shfl_xor(ss, m, 64);
        tt += __shfl_xor(tt, m, 64);
    }
    float sinv = 1.0f / fmaxf(sqrtf(ss), EPSN);
    float tinv = 1.0f / fmaxf(sqrtf(tt), EPSN);
    float2 sn = {sv.x * sinv, sv.y * sinv};
    float2 tn = {tv.x * tinv, tv.y * tinv};
    ((float2*)(s_n + b * D_SZ))[l] = sn;
    ((float2*)(t_n + b * D_SZ))[l] = tn;
    float d = sn.x * tn.x + sn.y * tn.y;
    for (int m = 1; m < 64; m <<= 1) d += __shfl_xor(d, m, 64);
    if (l == 0) pos[b] = d * (1.0f / TEMP);
}

// ---------------- copy: wave-contiguous tiles, register carry realign ----------------
// out[1+i] = bank[i]; wsb[j] = fp8(bank[4j..4j+3])
__global__ __launch_bounds__(256) void kcopy_emit(const float* __restrict__ src,
                                                  float* __restrict__ out /* d_out */,
                                                  unsigned int* __restrict__ wsb) {
    const long long total = (long long)NDATA * D_SZ;  // 64,000,000
    const int lane = threadIdx.x & 63;
    const long long wave_gid = (long long)blockIdx.x * 4 + (threadIdx.x >> 6);
    if (wave_gid >= NTILE) return;
    const long long base = wave_gid * TILE_V;  // first vector of this wave's tile
    const f32x4* src4 = (const f32x4*)src;
    f32x4* out4 = (f32x4*)out;
    float carry = 0.0f;
    if (lane == 0 && base > 0) carry = src[4 * base - 1];
#pragma unroll 4
    for (int it = 0; it < 16; ++it) {
        long long j = base + it * 64 + lane;
        f32x4 v = __builtin_nontemporal_load(src4 + j);
        int w8 = __builtin_amdgcn_cvt_pk_fp8_f32(v.x, v.y, 0, false);
        w8 = __builtin_amdgcn_cvt_pk_fp8_f32(v.z, v.w, w8, true);
        wsb[j] = (unsigned int)w8;  // regular store -> L3-resident for gather
        float pw = __shfl_up(v.w, 1, 64);
        if (lane == 0) pw = carry;
        carry = __shfl(v.w, 63, 64);  // lane63's last elem -> next iter's lane0
        if (j > 0) {
            f32x4 w;
            w.x = pw; w.y = v.x; w.z = v.y; w.w = v.z;
            __builtin_nontemporal_store(w, out4 + j);
        } else {
            out[1] = v.x; out[2] = v.y; out[3] = v.z;
            out[total] = src[total - 1];
        }
    }
}

// ---------------- fp8 dot helper: 16 elements vs s-chunk ----------------
__device__ __forceinline__ float dot16_fp8(uint4 h, f32x4 s0, f32x4 s1, f32x4 s2, f32x4 s3) {
    float d = 0.0f;
    f32x2 a, c;
    a = __builtin_amdgcn_cvt_pk_f32_fp8((int)h.x, false);
    c = __builtin_amdgcn_cvt_pk_f32_fp8((int)h.x, true);
    d += a.x * s0.x + a.y * s0.y + c.x * s0.z + c.y * s0.w;
    a = __builtin_amdgcn_cvt_pk_f32_fp8((int)h.y, false);
    c = __builtin_amdgcn_cvt_pk_f32_fp8((int)h.y, true);
    d += a.x * s1.x + a.y * s1.y + c.x * s1.z + c.y * s1.w;
    a = __builtin_amdgcn_cvt_pk_f32_fp8((int)h.z, false);
    c = __builtin_amdgcn_cvt_pk_f32_fp8((int)h.z, true);
    d += a.x * s2.x + a.y * s2.y + c.x * s2.z + c.y * s2.w;
    a = __builtin_amdgcn_cvt_pk_f32_fp8((int)h.w, false);
    c = __builtin_amdgcn_cvt_pk_f32_fp8((int)h.w, true);
    d += a.x * s3.x + a.y * s3.y + c.x * s3.z + c.y * s3.w;
    return d;
}

// ---------------- gather from fp8 shadow: 8 lanes/row, 8 rows in flight ----------------
__global__ __launch_bounds__(256) void kneg_fp8(const unsigned int* __restrict__ wsb,
                                                const int* __restrict__ negidx,
                                                const float* __restrict__ s_n,
                                                float2* __restrict__ partials) {
    const int split = blockIdx.x;  // 0..SPLIT-1
    const int b = blockIdx.y;
    const int tid = threadIdx.x;
    const int oct = tid >> 3;  // 32 octets of 8 lanes
    const int o = tid & 7;
    const f32x4* sn4 = (const f32x4*)(s_n + b * D_SZ + o * 16);
    f32x4 s0 = sn4[0], s1 = sn4[1], s2 = sn4[2], s3 = sn4[3];
    float m = -INFINITY, ssum = 0.0f;
    const int KB = K_SZ / SPLIT;             // 512 rows per block
    const int base = b * K_SZ + split * KB;
    for (int it = 0; it < KB / 256; ++it) {  // 2 iters; octet does 8 rows/iter
        int k = it * 256 + oct * 8;
        int4 ia = *(const int4*)(negidx + base + k);
        int4 ib = *(const int4*)(negidx + base + k + 4);
        uint4 h0 = ((const uint4*)(wsb + (long long)ia.x * 32))[o];
        uint4 h1 = ((const uint4*)(wsb + (long long)ia.y * 32))[o];
        uint4 h2 = ((const uint4*)(wsb + (long long)ia.z * 32))[o];
        uint4 h3 = ((const uint4*)(wsb + (long long)ia.w * 32))[o];
        uint4 h4 = ((const uint4*)(wsb + (long long)ib.x * 32))[o];
        uint4 h5 = ((const uint4*)(wsb + (long long)ib.y * 32))[o];
        uint4 h6 = ((const uint4*)(wsb + (long long)ib.z * 32))[o];
        uint4 h7 = ((const uint4*)(wsb + (long long)ib.w * 32))[o];
        float d0 = dot16_fp8(h0, s0, s1, s2, s3);
        float d1 = dot16_fp8(h1, s0, s1, s2, s3);
        float d2 = dot16_fp8(h2, s0, s1, s2, s3);
        float d3 = dot16_fp8(h3, s0, s1, s2, s3);
        float d4 = dot16_fp8(h4, s0, s1, s2, s3);
        float d5 = dot16_fp8(h5, s0, s1, s2, s3);
        float d6 = dot16_fp8(h6, s0, s1, s2, s3);
        float d7 = dot16_fp8(h7, s0, s1, s2, s3);
        for (int s = 1; s < 8; s <<= 1) {
            d0 += __shfl_xor(d0, s, 64);
            d1 += __shfl_xor(d1, s, 64);
            d2 += __shfl_xor(d2, s, 64);
            d3 += __shfl_xor(d3, s, 64);
            d4 += __shfl_xor(d4, s, 64);
            d5 += __shfl_xor(d5, s, 64);
            d6 += __shfl_xor(d6, s, 64);
            d7 += __shfl_xor(d7, s, 64);
        }
        d0 *= (1.0f / TEMP); d1 *= (1.0f / TEMP); d2 *= (1.0f / TEMP); d3 *= (1.0f / TEMP);
        d4 *= (1.0f / TEMP); d5 *= (1.0f / TEMP); d6 *= (1.0f / TEMP); d7 *= (1.0f / TEMP);
        float mx = fmaxf(fmaxf(fmaxf(d0, d1), fmaxf(d2, d3)),
                         fmaxf(fmaxf(d4, d5), fmaxf(d6, d7)));
        float mn = fmaxf(m, mx);
        ssum = ssum * __expf(m - mn) + __expf(d0 - mn) + __expf(d1 - mn) +
               __expf(d2 - mn) + __expf(d3 - mn) + __expf(d4 - mn) +
               __expf(d5 - mn) + __expf(d6 - mn) + __expf(d7 - mn);
        m = mn;
    }
    __shared__ float2 gp[32];
    if (o == 0) gp[oct] = make_float2(m, ssum);
    __syncthreads();
    if (tid == 0) {
        float M = gp[0].x, S = gp[0].y;
        for (int g = 1; g < 32; ++g) {
            float mg = gp[g].x, sg = gp[g].y;
            float mn = fmaxf(M, mg);
            S = S * __expf(M - mn) + sg * __expf(mg - mn);
            M = mn;
        }
        partials[b * SPLIT + split] = make_float2(M, S);
    }
}

// ---------------- momentum scatter-update (last-wins) ----------------
__global__ void kupdate(const int* __restrict__ indices, const float* __restrict__ bank,
                        const float* __restrict__ t_n, float* __restrict__ outBank /* d_out+1 */) {
    int j = blockIdx.x;
    int l = threadIdx.x;  // 64
    int idx = indices[j];
    for (int j2 = j + 1; j2 < B_SZ; ++j2)
        if (indices[j2] == idx) return;  // last occurrence wins
    float2 bv = ((const float2*)(bank + (long long)idx * D_SZ))[l];
    float2 tv = ((const float2*)(t_n + j * D_SZ))[l];
    float2 u = {MOM * bv.x + (1.0f - MOM) * tv.x, MOM * bv.y + (1.0f - MOM) * tv.y};
    float ss = u.x * u.x + u.y * u.y;
    for (int m = 1; m < 64; m <<= 1) ss += __shfl_xor(ss, m, 64);
    float inv = 1.0f / fmaxf(sqrtf(ss), EPSN);
    float* dst = outBank + (long long)idx * D_SZ + l * 2;
    dst[0] = u.x * inv;
    dst[1] = u.y * inv;
}

// ---------------- combine partials -> loss ----------------
__global__ void kfinal(const float2* __restrict__ partials, const float* __restrict__ pos,
                       float* __restrict__ out) {
    __shared__ float red[B_SZ];
    int t = threadIdx.x;  // 512
    float M = -INFINITY, S = 0.0f;
    for (int p = 0; p < SPLIT; ++p) {
        float2 ms = partials[t * SPLIT + p];
        float mn = fmaxf(M, ms.x);
        S = S * __expf(M - mn) + ms.y * __expf(ms.x - mn);
        M = mn;
    }
    float pl = pos[t];
    float mn = fmaxf(M, pl);
    S = S * __expf(M - mn) + __expf(pl - mn);
    M = mn;
    red[t] = M + logf(S) - pl;
    __syncthreads();
    for (int o = 256; o > 0; o >>= 1) {
        if (t < o) red[t] += red[t + o];
        __syncthreads();
    }
    if (t == 0) out[0] = red[0] * (1.0f / (float)B_SZ);
}

extern "C" void kernel_launch(void* const* d_in, const int* in_sizes, int n_in,
                              void* d_out, int out_size, void* d_ws, size_t ws_size,
                              hipStream_t stream) {
    const float* student = (const float*)d_in[0];
    const float* teacher = (const float*)d_in[1];
    const float* bank    = (const float*)d_in[2];
    const int*   indices = (const int*)d_in[3];
    const int*   negidx  = (const int*)d_in[4];
    float* out = (float*)d_out;

    // workspace: small arrays in first 1 MB, fp8 shadow bank after (61 MB)
    float* s_n      = (float*)d_ws;              // 65536 f
    float* t_n      = s_n + B_SZ * D_SZ;         // 65536 f
    float* pos      = t_n + B_SZ * D_SZ;         // 512 f
    float2* partials = (float2*)(pos + B_SZ);    // 512*SPLIT float2
    unsigned int* wsb = (unsigned int*)((char*)d_ws + WSB_OFF);

    knorm<<<B_SZ, 64, 0, stream>>>(student, teacher, s_n, t_n, pos);
    kcopy_emit<<<3907, 256, 0, stream>>>(bank, out, wsb);  // 15628 waves, 15625 tiles
    dim3 g(SPLIT, B_SZ);
    kneg_fp8<<<g, 256, 0, stream>>>(wsb, negidx, s_n, partials);
    kupdate<<<B_SZ, 64, 0, stream>>>(indices, bank, t_n, out + 1);
    kfinal<<<1, B_SZ, 0, stream>>>(partials, pos, out);
}

// Round 12
// 172.974 us; speedup vs baseline: 1.1778x; 1.0338x over previous
//
#include <hip/hip_runtime.h>
#include <cmath>

#define B_SZ 512
#define D_SZ 128
#define K_SZ 4096
#define NDATA 500000
#define TEMP 0.07f
#define MOM 0.5f
#define EPSN 1e-12f
#define SPLIT 8
#define WSB_OFF (1 << 20)  // fp8 shadow bank offset in d_ws (bytes)

typedef float f32x4 __attribute__((ext_vector_type(4)));
typedef float f32x2 __attribute__((ext_vector_type(2)));

// ---------------- kernel A: normalize s,t + pos logits ----------------
__global__ void knorm(const float* __restrict__ s_in, const float* __restrict__ t_in,
                      float* __restrict__ s_n, float* __restrict__ t_n,
                      float* __restrict__ pos) {
    int b = blockIdx.x;
    int l = threadIdx.x;  // 64 lanes, 2 floats each
    float2 sv = ((const float2*)(s_in + b * D_SZ))[l];
    float2 tv = ((const float2*)(t_in + b * D_SZ))[l];
    float ss = sv.x * sv.x + sv.y * sv.y;
    float tt = tv.x * tv.x + tv.y * tv.y;
    for (int m = 1; m < 64; m <<= 1) {
        ss += __shfl_xor(ss, m, 64);
        tt += __shfl_xor(tt, m, 64);
    }
    float sinv = 1.0f / fmaxf(sqrtf(ss), EPSN);
    float tinv = 1.0f / fmaxf(sqrtf(tt), EPSN);
    float2 sn = {sv.x * sinv, sv.y * sinv};
    float2 tn = {tv.x * tinv, tv.y * tinv};
    ((float2*)(s_n + b * D_SZ))[l] = sn;
    ((float2*)(t_n + b * D_SZ))[l] = tn;
    float d = sn.x * tn.x + sn.y * tn.y;
    for (int m = 1; m < 64; m <<= 1) d += __shfl_xor(d, m, 64);
    if (l == 0) pos[b] = d * (1.0f / TEMP);
}

// ---------------- copy: plain cached loads + NT out-store + fp8 shadow ----------------
// out[1+i] = bank[i]; wsb[j] = fp8(bank[4j..4j+3])
__global__ __launch_bounds__(256) void kcopy_emit(const float* __restrict__ src,
                                                  float* __restrict__ out /* d_out */,
                                                  unsigned int* __restrict__ wsb) {
    const long long total = (long long)NDATA * D_SZ;  // 64,000,000
    const long long NV = total / 4;                   // 16,000,000
    long long t = blockIdx.x * 256LL + threadIdx.x;
    const long long nthr = gridDim.x * 256LL;
    const int lane = threadIdx.x & 63;
    const f32x4* src4 = (const f32x4*)src;
    f32x4* out4 = (f32x4*)out;
    for (long long j = t; j < NV; j += nthr) {
        f32x4 v = src4[j];  // plain cached load (streaming read)
        int w8 = __builtin_amdgcn_cvt_pk_fp8_f32(v.x, v.y, 0, false);
        w8 = __builtin_amdgcn_cvt_pk_fp8_f32(v.z, v.w, w8, true);
        wsb[j] = (unsigned int)w8;  // regular store -> L3-resident for gather
        float pw = __shfl_up(v.w, 1, 64);
        if (lane == 0 && j > 0) pw = src[4 * j - 1];  // cache-hit neighbor
        if (j > 0) {
            f32x4 w;
            w.x = pw; w.y = v.x; w.z = v.y; w.w = v.z;
            __builtin_nontemporal_store(w, out4 + j);
        } else {
            out[1] = v.x; out[2] = v.y; out[3] = v.z;
            out[total] = src[total - 1];
        }
    }
}

// ---------------- fp8 dot helper: 16 elements vs s-chunk ----------------
__device__ __forceinline__ float dot16_fp8(uint4 h, f32x4 s0, f32x4 s1, f32x4 s2, f32x4 s3) {
    float d = 0.0f;
    f32x2 a, c;
    a = __builtin_amdgcn_cvt_pk_f32_fp8((int)h.x, false);
    c = __builtin_amdgcn_cvt_pk_f32_fp8((int)h.x, true);
    d += a.x * s0.x + a.y * s0.y + c.x * s0.z + c.y * s0.w;
    a = __builtin_amdgcn_cvt_pk_f32_fp8((int)h.y, false);
    c = __builtin_amdgcn_cvt_pk_f32_fp8((int)h.y, true);
    d += a.x * s1.x + a.y * s1.y + c.x * s1.z + c.y * s1.w;
    a = __builtin_amdgcn_cvt_pk_f32_fp8((int)h.z, false);
    c = __builtin_amdgcn_cvt_pk_f32_fp8((int)h.z, true);
    d += a.x * s2.x + a.y * s2.y + c.x * s2.z + c.y * s2.w;
    a = __builtin_amdgcn_cvt_pk_f32_fp8((int)h.w, false);
    c = __builtin_amdgcn_cvt_pk_f32_fp8((int)h.w, true);
    d += a.x * s3.x + a.y * s3.y + c.x * s3.z + c.y * s3.w;
    return d;
}

// ---------------- gather from fp8 shadow: 8 lanes/row, 8 rows in flight ----------------
__global__ __launch_bounds__(256) void kneg_fp8(const unsigned int* __restrict__ wsb,
                                                const int* __restrict__ negidx,
                                                const float* __restrict__ s_n,
                                                float2* __restrict__ partials) {
    const int split = blockIdx.x;  // 0..SPLIT-1
    const int b = blockIdx.y;
    const int tid = threadIdx.x;
    const int oct = tid >> 3;  // 32 octets of 8 lanes
    const int o = tid & 7;
    const f32x4* sn4 = (const f32x4*)(s_n + b * D_SZ + o * 16);
    f32x4 s0 = sn4[0], s1 = sn4[1], s2 = sn4[2], s3 = sn4[3];
    float m = -INFINITY, ssum = 0.0f;
    const int KB = K_SZ / SPLIT;             // 512 rows per block
    const int base = b * K_SZ + split * KB;
    for (int it = 0; it < KB / 256; ++it) {  // 2 iters; octet does 8 rows/iter
        int k = it * 256 + oct * 8;
        int4 ia = *(const int4*)(negidx + base + k);
        int4 ib = *(const int4*)(negidx + base + k + 4);
        uint4 h0 = ((const uint4*)(wsb + (long long)ia.x * 32))[o];
        uint4 h1 = ((const uint4*)(wsb + (long long)ia.y * 32))[o];
        uint4 h2 = ((const uint4*)(wsb + (long long)ia.z * 32))[o];
        uint4 h3 = ((const uint4*)(wsb + (long long)ia.w * 32))[o];
        uint4 h4 = ((const uint4*)(wsb + (long long)ib.x * 32))[o];
        uint4 h5 = ((const uint4*)(wsb + (long long)ib.y * 32))[o];
        uint4 h6 = ((const uint4*)(wsb + (long long)ib.z * 32))[o];
        uint4 h7 = ((const uint4*)(wsb + (long long)ib.w * 32))[o];
        float d0 = dot16_fp8(h0, s0, s1, s2, s3);
        float d1 = dot16_fp8(h1, s0, s1, s2, s3);
        float d2 = dot16_fp8(h2, s0, s1, s2, s3);
        float d3 = dot16_fp8(h3, s0, s1, s2, s3);
        float d4 = dot16_fp8(h4, s0, s1, s2, s3);
        float d5 = dot16_fp8(h5, s0, s1, s2, s3);
        float d6 = dot16_fp8(h6, s0, s1, s2, s3);
        float d7 = dot16_fp8(h7, s0, s1, s2, s3);
        for (int s = 1; s < 8; s <<= 1) {
            d0 += __shfl_xor(d0, s, 64);
            d1 += __shfl_xor(d1, s, 64);
            d2 += __shfl_xor(d2, s, 64);
            d3 += __shfl_xor(d3, s, 64);
            d4 += __shfl_xor(d4, s, 64);
            d5 += __shfl_xor(d5, s, 64);
            d6 += __shfl_xor(d6, s, 64);
            d7 += __shfl_xor(d7, s, 64);
        }
        d0 *= (1.0f / TEMP); d1 *= (1.0f / TEMP); d2 *= (1.0f / TEMP); d3 *= (1.0f / TEMP);
        d4 *= (1.0f / TEMP); d5 *= (1.0f / TEMP); d6 *= (1.0f / TEMP); d7 *= (1.0f / TEMP);
        float mx = fmaxf(fmaxf(fmaxf(d0, d1), fmaxf(d2, d3)),
                         fmaxf(fmaxf(d4, d5), fmaxf(d6, d7)));
        float mn = fmaxf(m, mx);
        ssum = ssum * __expf(m - mn) + __expf(d0 - mn) + __expf(d1 - mn) +
               __expf(d2 - mn) + __expf(d3 - mn) + __expf(d4 - mn) +
               __expf(d5 - mn) + __expf(d6 - mn) + __expf(d7 - mn);
        m = mn;
    }
    __shared__ float2 gp[32];
    if (o == 0) gp[oct] = make_float2(m, ssum);
    __syncthreads();
    if (tid == 0) {
        float M = gp[0].x, S = gp[0].y;
        for (int g = 1; g < 32; ++g) {
            float mg = gp[g].x, sg = gp[g].y;
            float mn = fmaxf(M, mg);
            S = S * __expf(M - mn) + sg * __expf(mg - mn);
            M = mn;
        }
        partials[b * SPLIT + split] = make_float2(M, S);
    }
}

// ---------------- momentum scatter-update (last-wins) ----------------
__global__ void kupdate(const int* __restrict__ indices, const float* __restrict__ bank,
                        const float* __restrict__ t_n, float* __restrict__ outBank /* d_out+1 */) {
    int j = blockIdx.x;
    int l = threadIdx.x;  // 64
    int idx = indices[j];
    for (int j2 = j + 1; j2 < B_SZ; ++j2)
        if (indices[j2] == idx) return;  // last occurrence wins
    float2 bv = ((const float2*)(bank + (long long)idx * D_SZ))[l];
    float2 tv = ((const float2*)(t_n + j * D_SZ))[l];
    float2 u = {MOM * bv.x + (1.0f - MOM) * tv.x, MOM * bv.y + (1.0f - MOM) * tv.y};
    float ss = u.x * u.x + u.y * u.y;
    for (int m = 1; m < 64; m <<= 1) ss += __shfl_xor(ss, m, 64);
    float inv = 1.0f / fmaxf(sqrtf(ss), EPSN);
    float* dst = outBank + (long long)idx * D_SZ + l * 2;
    dst[0] = u.x * inv;
    dst[1] = u.y * inv;
}

// ---------------- combine partials -> loss ----------------
__global__ void kfinal(const float2* __restrict__ partials, const float* __restrict__ pos,
                       float* __restrict__ out) {
    __shared__ float red[B_SZ];
    int t = threadIdx.x;  // 512
    float M = -INFINITY, S = 0.0f;
    for (int p = 0; p < SPLIT; ++p) {
        float2 ms = partials[t * SPLIT + p];
        float mn = fmaxf(M, ms.x);
        S = S * __expf(M - mn) + ms.y * __expf(ms.x - mn);
        M = mn;
    }
    float pl = pos[t];
    float mn = fmaxf(M, pl);
    S = S * __expf(M - mn) + __expf(pl - mn);
    M = mn;
    red[t] = M + logf(S) - pl;
    __syncthreads();
    for (int o = 256; o > 0; o >>= 1) {
        if (t < o) red[t] += red[t + o];
        __syncthreads();
    }
    if (t == 0) out[0] = red[0] * (1.0f / (float)B_SZ);
}

extern "C" void kernel_launch(void* const* d_in, const int* in_sizes, int n_in,
                              void* d_out, int out_size, void* d_ws, size_t ws_size,
                              hipStream_t stream) {
    const float* student = (const float*)d_in[0];
    const float* teacher = (const float*)d_in[1];
    const float* bank    = (const float*)d_in[2];
    const int*   indices = (const int*)d_in[3];
    const int*   negidx  = (const int*)d_in[4];
    float* out = (float*)d_out;

    // workspace: small arrays in first 1 MB, fp8 shadow bank after (61 MB)
    float* s_n      = (float*)d_ws;              // 65536 f
    float* t_n      = s_n + B_SZ * D_SZ;         // 65536 f
    float* pos      = t_n + B_SZ * D_SZ;         // 512 f
    float2* partials = (float2*)(pos + B_SZ);    // 512*SPLIT float2
    unsigned int* wsb = (unsigned int*)((char*)d_ws + WSB_OFF);

    knorm<<<B_SZ, 64, 0, stream>>>(student, teacher, s_n, t_n, pos);
    kcopy_emit<<<4096, 256, 0, stream>>>(bank, out, wsb);
    dim3 g(SPLIT, B_SZ);
    kneg_fp8<<<g, 256, 0, stream>>>(wsb, negidx, s_n, partials);
    kupdate<<<B_SZ, 64, 0, stream>>>(indices, bank, t_n, out + 1);
    kfinal<<<1, B_SZ, 0, stream>>>(partials, pos, out);
}

// Round 13
// 171.549 us; speedup vs baseline: 1.1876x; 1.0083x over previous
//
#include <hip/hip_runtime.h>
#include <cmath>

#define B_SZ 512
#define D_SZ 128
#define K_SZ 4096
#define NDATA 500000
#define TEMP 0.07f
#define MOM 0.5f
#define EPSN 1e-12f
#define SPLIT 8
#define WSB_OFF (1 << 20)   // fp8 shadow bank offset in d_ws (bytes)
#define NV_TOT 16000000LL   // total float4 vectors in bank
#define NTILES 62500LL      // NV_TOT / 256

typedef float f32x4 __attribute__((ext_vector_type(4)));
typedef float f32x2 __attribute__((ext_vector_type(2)));

// ---------------- kernel A: normalize s,t + pos logits ----------------
__global__ void knorm(const float* __restrict__ s_in, const float* __restrict__ t_in,
                      float* __restrict__ s_n, float* __restrict__ t_n,
                      float* __restrict__ pos) {
    int b = blockIdx.x;
    int l = threadIdx.x;  // 64 lanes, 2 floats each
    float2 sv = ((const float2*)(s_in + b * D_SZ))[l];
    float2 tv = ((const float2*)(t_in + b * D_SZ))[l];
    float ss = sv.x * sv.x + sv.y * sv.y;
    float tt = tv.x * tv.x + tv.y * tv.y;
    for (int m = 1; m < 64; m <<= 1) {
        ss += __shfl_xor(ss, m, 64);
        tt += __shfl_xor(tt, m, 64);
    }
    float sinv = 1.0f / fmaxf(sqrtf(ss), EPSN);
    float tinv = 1.0f / fmaxf(sqrtf(tt), EPSN);
    float2 sn = {sv.x * sinv, sv.y * sinv};
    float2 tn = {tv.x * tinv, tv.y * tinv};
    ((float2*)(s_n + b * D_SZ))[l] = sn;
    ((float2*)(t_n + b * D_SZ))[l] = tn;
    float d = sn.x * tn.x + sn.y * tn.y;
    for (int m = 1; m < 64; m <<= 1) d += __shfl_xor(d, m, 64);
    if (l == 0) pos[b] = d * (1.0f / TEMP);
}

// ---------------- copy: wave tiles of 256 vectors, 4 batched loads ----------------
// out[1+i] = bank[i]; wsb[j] = fp8(bank[4j..4j+3])
__global__ __launch_bounds__(256) void kcopy_emit(const float* __restrict__ src,
                                                  float* __restrict__ out /* d_out */,
                                                  unsigned int* __restrict__ wsb) {
    const long long total = (long long)NDATA * D_SZ;  // 64,000,000
    const int lane = threadIdx.x & 63;
    const long long nwaves = (long long)gridDim.x * 4;
    const long long w = (long long)blockIdx.x * 4 + (threadIdx.x >> 6);
    const f32x4* src4 = (const f32x4*)src;
    f32x4* out4 = (f32x4*)out;
    for (long long tile = w; tile < NTILES; tile += nwaves) {
        const long long base = tile * 256;
        // 4 independent loads in flight
        f32x4 v0 = src4[base + lane];
        f32x4 v1 = src4[base + 64 + lane];
        f32x4 v2 = src4[base + 128 + lane];
        f32x4 v3 = src4[base + 192 + lane];
        float carry = 0.0f;
        if (lane == 0 && base > 0) carry = src[4 * base - 1];  // 1 scalar/tile
        // fp8 shadow emits (regular stores -> L3-resident)
        int w8;
        w8 = __builtin_amdgcn_cvt_pk_fp8_f32(v0.x, v0.y, 0, false);
        w8 = __builtin_amdgcn_cvt_pk_fp8_f32(v0.z, v0.w, w8, true);
        wsb[base + lane] = (unsigned int)w8;
        w8 = __builtin_amdgcn_cvt_pk_fp8_f32(v1.x, v1.y, 0, false);
        w8 = __builtin_amdgcn_cvt_pk_fp8_f32(v1.z, v1.w, w8, true);
        wsb[base + 64 + lane] = (unsigned int)w8;
        w8 = __builtin_amdgcn_cvt_pk_fp8_f32(v2.x, v2.y, 0, false);
        w8 = __builtin_amdgcn_cvt_pk_fp8_f32(v2.z, v2.w, w8, true);
        wsb[base + 128 + lane] = (unsigned int)w8;
        w8 = __builtin_amdgcn_cvt_pk_fp8_f32(v3.x, v3.y, 0, false);
        w8 = __builtin_amdgcn_cvt_pk_fp8_f32(v3.z, v3.w, w8, true);
        wsb[base + 192 + lane] = (unsigned int)w8;
        // realign across lanes/sub-iterations
        float pw0 = __shfl_up(v0.w, 1, 64);
        float c0 = __shfl(v0.w, 63, 64);
        float pw1 = __shfl_up(v1.w, 1, 64);
        float c1 = __shfl(v1.w, 63, 64);
        float pw2 = __shfl_up(v2.w, 1, 64);
        float c2 = __shfl(v2.w, 63, 64);
        float pw3 = __shfl_up(v3.w, 1, 64);
        if (lane == 0) { pw0 = carry; pw1 = c0; pw2 = c1; pw3 = c2; }
        // out stores (NT, 4B-shifted via realigned vectors)
        long long j = base + lane;
        if (j > 0) {
            f32x4 t0; t0.x = pw0; t0.y = v0.x; t0.z = v0.y; t0.w = v0.z;
            __builtin_nontemporal_store(t0, out4 + j);
        } else {
            out[1] = v0.x; out[2] = v0.y; out[3] = v0.z;
            out[total] = src[total - 1];
        }
        f32x4 t1; t1.x = pw1; t1.y = v1.x; t1.z = v1.y; t1.w = v1.z;
        __builtin_nontemporal_store(t1, out4 + base + 64 + lane);
        f32x4 t2; t2.x = pw2; t2.y = v2.x; t2.z = v2.y; t2.w = v2.z;
        __builtin_nontemporal_store(t2, out4 + base + 128 + lane);
        f32x4 t3; t3.x = pw3; t3.y = v3.x; t3.z = v3.y; t3.w = v3.z;
        __builtin_nontemporal_store(t3, out4 + base + 192 + lane);
    }
}

// ---------------- fp8 dot helper: 16 elements vs s-chunk ----------------
__device__ __forceinline__ float dot16_fp8(uint4 h, f32x4 s0, f32x4 s1, f32x4 s2, f32x4 s3) {
    float d = 0.0f;
    f32x2 a, c;
    a = __builtin_amdgcn_cvt_pk_f32_fp8((int)h.x, false);
    c = __builtin_amdgcn_cvt_pk_f32_fp8((int)h.x, true);
    d += a.x * s0.x + a.y * s0.y + c.x * s0.z + c.y * s0.w;
    a = __builtin_amdgcn_cvt_pk_f32_fp8((int)h.y, false);
    c = __builtin_amdgcn_cvt_pk_f32_fp8((int)h.y, true);
    d += a.x * s1.x + a.y * s1.y + c.x * s1.z + c.y * s1.w;
    a = __builtin_amdgcn_cvt_pk_f32_fp8((int)h.z, false);
    c = __builtin_amdgcn_cvt_pk_f32_fp8((int)h.z, true);
    d += a.x * s2.x + a.y * s2.y + c.x * s2.z + c.y * s2.w;
    a = __builtin_amdgcn_cvt_pk_f32_fp8((int)h.w, false);
    c = __builtin_amdgcn_cvt_pk_f32_fp8((int)h.w, true);
    d += a.x * s3.x + a.y * s3.y + c.x * s3.z + c.y * s3.w;
    return d;
}

// ---------------- gather from fp8 shadow: 8 lanes/row, 8 rows in flight ----------------
__global__ __launch_bounds__(256) void kneg_fp8(const unsigned int* __restrict__ wsb,
                                                const int* __restrict__ negidx,
                                                const float* __restrict__ s_n,
                                                float2* __restrict__ partials) {
    const int split = blockIdx.x;  // 0..SPLIT-1
    const int b = blockIdx.y;
    const int tid = threadIdx.x;
    const int oct = tid >> 3;  // 32 octets of 8 lanes
    const int o = tid & 7;
    const f32x4* sn4 = (const f32x4*)(s_n + b * D_SZ + o * 16);
    f32x4 s0 = sn4[0], s1 = sn4[1], s2 = sn4[2], s3 = sn4[3];
    float m = -INFINITY, ssum = 0.0f;
    const int KB = K_SZ / SPLIT;             // 512 rows per block
    const int base = b * K_SZ + split * KB;
    for (int it = 0; it < KB / 256; ++it) {  // 2 iters; octet does 8 rows/iter
        int k = it * 256 + oct * 8;
        int4 ia = *(const int4*)(negidx + base + k);
        int4 ib = *(const int4*)(negidx + base + k + 4);
        uint4 h0 = ((const uint4*)(wsb + (long long)ia.x * 32))[o];
        uint4 h1 = ((const uint4*)(wsb + (long long)ia.y * 32))[o];
        uint4 h2 = ((const uint4*)(wsb + (long long)ia.z * 32))[o];
        uint4 h3 = ((const uint4*)(wsb + (long long)ia.w * 32))[o];
        uint4 h4 = ((const uint4*)(wsb + (long long)ib.x * 32))[o];
        uint4 h5 = ((const uint4*)(wsb + (long long)ib.y * 32))[o];
        uint4 h6 = ((const uint4*)(wsb + (long long)ib.z * 32))[o];
        uint4 h7 = ((const uint4*)(wsb + (long long)ib.w * 32))[o];
        float d0 = dot16_fp8(h0, s0, s1, s2, s3);
        float d1 = dot16_fp8(h1, s0, s1, s2, s3);
        float d2 = dot16_fp8(h2, s0, s1, s2, s3);
        float d3 = dot16_fp8(h3, s0, s1, s2, s3);
        float d4 = dot16_fp8(h4, s0, s1, s2, s3);
        float d5 = dot16_fp8(h5, s0, s1, s2, s3);
        float d6 = dot16_fp8(h6, s0, s1, s2, s3);
        float d7 = dot16_fp8(h7, s0, s1, s2, s3);
        for (int s = 1; s < 8; s <<= 1) {
            d0 += __shfl_xor(d0, s, 64);
            d1 += __shfl_xor(d1, s, 64);
            d2 += __shfl_xor(d2, s, 64);
            d3 += __shfl_xor(d3, s, 64);
            d4 += __shfl_xor(d4, s, 64);
            d5 += __shfl_xor(d5, s, 64);
            d6 += __shfl_xor(d6, s, 64);
            d7 += __shfl_xor(d7, s, 64);
        }
        d0 *= (1.0f / TEMP); d1 *= (1.0f / TEMP); d2 *= (1.0f / TEMP); d3 *= (1.0f / TEMP);
        d4 *= (1.0f / TEMP); d5 *= (1.0f / TEMP); d6 *= (1.0f / TEMP); d7 *= (1.0f / TEMP);
        float mx = fmaxf(fmaxf(fmaxf(d0, d1), fmaxf(d2, d3)),
                         fmaxf(fmaxf(d4, d5), fmaxf(d6, d7)));
        float mn = fmaxf(m, mx);
        ssum = ssum * __expf(m - mn) + __expf(d0 - mn) + __expf(d1 - mn) +
               __expf(d2 - mn) + __expf(d3 - mn) + __expf(d4 - mn) +
               __expf(d5 - mn) + __expf(d6 - mn) + __expf(d7 - mn);
        m = mn;
    }
    __shared__ float2 gp[32];
    if (o == 0) gp[oct] = make_float2(m, ssum);
    __syncthreads();
    if (tid == 0) {
        float M = gp[0].x, S = gp[0].y;
        for (int g = 1; g < 32; ++g) {
            float mg = gp[g].x, sg = gp[g].y;
            float mn = fmaxf(M, mg);
            S = S * __expf(M - mn) + sg * __expf(mg - mn);
            M = mn;
        }
        partials[b * SPLIT + split] = make_float2(M, S);
    }
}

// ---------------- momentum scatter-update (last-wins) ----------------
__global__ void kupdate(const int* __restrict__ indices, const float* __restrict__ bank,
                        const float* __restrict__ t_n, float* __restrict__ outBank /* d_out+1 */) {
    int j = blockIdx.x;
    int l = threadIdx.x;  // 64
    int idx = indices[j];
    for (int j2 = j + 1; j2 < B_SZ; ++j2)
        if (indices[j2] == idx) return;  // last occurrence wins
    float2 bv = ((const float2*)(bank + (long long)idx * D_SZ))[l];
    float2 tv = ((const float2*)(t_n + j * D_SZ))[l];
    float2 u = {MOM * bv.x + (1.0f - MOM) * tv.x, MOM * bv.y + (1.0f - MOM) * tv.y};
    float ss = u.x * u.x + u.y * u.y;
    for (int m = 1; m < 64; m <<= 1) ss += __shfl_xor(ss, m, 64);
    float inv = 1.0f / fmaxf(sqrtf(ss), EPSN);
    float* dst = outBank + (long long)idx * D_SZ + l * 2;
    dst[0] = u.x * inv;
    dst[1] = u.y * inv;
}

// ---------------- combine partials -> loss ----------------
__global__ void kfinal(const float2* __restrict__ partials, const float* __restrict__ pos,
                       float* __restrict__ out) {
    __shared__ float red[B_SZ];
    int t = threadIdx.x;  // 512
    float M = -INFINITY, S = 0.0f;
    for (int p = 0; p < SPLIT; ++p) {
        float2 ms = partials[t * SPLIT + p];
        float mn = fmaxf(M, ms.x);
        S = S * __expf(M - mn) + ms.y * __expf(ms.x - mn);
        M = mn;
    }
    float pl = pos[t];
    float mn = fmaxf(M, pl);
    S = S * __expf(M - mn) + __expf(pl - mn);
    M = mn;
    red[t] = M + logf(S) - pl;
    __syncthreads();
    for (int o = 256; o > 0; o >>= 1) {
        if (t < o) red[t] += red[t + o];
        __syncthreads();
    }
    if (t == 0) out[0] = red[0] * (1.0f / (float)B_SZ);
}

extern "C" void kernel_launch(void* const* d_in, const int* in_sizes, int n_in,
                              void* d_out, int out_size, void* d_ws, size_t ws_size,
                              hipStream_t stream) {
    const float* student = (const float*)d_in[0];
    const float* teacher = (const float*)d_in[1];
    const float* bank    = (const float*)d_in[2];
    const int*   indices = (const int*)d_in[3];
    const int*   negidx  = (const int*)d_in[4];
    float* out = (float*)d_out;

    // workspace: small arrays in first 1 MB, fp8 shadow bank after (61 MB)
    float* s_n      = (float*)d_ws;              // 65536 f
    float* t_n      = s_n + B_SZ * D_SZ;         // 65536 f
    float* pos      = t_n + B_SZ * D_SZ;         // 512 f
    float2* partials = (float2*)(pos + B_SZ);    // 512*SPLIT float2
    unsigned int* wsb = (unsigned int*)((char*)d_ws + WSB_OFF);

    knorm<<<B_SZ, 64, 0, stream>>>(student, teacher, s_n, t_n, pos);
    kcopy_emit<<<4096, 256, 0, stream>>>(bank, out, wsb);
    dim3 g(SPLIT, B_SZ);
    kneg_fp8<<<g, 256, 0, stream>>>(wsb, negidx, s_n, partials);
    kupdate<<<B_SZ, 64, 0, stream>>>(indices, bank, t_n, out + 1);
    kfinal<<<1, B_SZ, 0, stream>>>(partials, pos, out);
}